// Round 8
// baseline (97.717 us; speedup 1.0000x reference)
//
#include <hip/hip_runtime.h>

#define CS   224
#define HH   1024
#define WW   1024
#define HW   (HH * WW)
#define RT   16              // rows per column tile
#define NTIL (HH / RT)       // 64
#define NCOLG 2              // 1024 cols / (256 threads * 2 floats)
#define LSEG 1026            // LDS segment: s+1 <= 1025, +1 pad

// ---- Pass 1: per-row inclusive cumsum into I (3072 blocks) -----------------
__global__ __launch_bounds__(256) void row_cumsum(
    const float* __restrict__ x, float* __restrict__ I)
{
    int row = blockIdx.x;                       // 0 .. 3*1024-1
    const float4* src = (const float4*)(x + (size_t)row * WW);
    float4*       dst = (float4*)(I + (size_t)row * WW);

    int t    = threadIdx.x;
    int lane = t & 63;
    int w    = t >> 6;

    float4 v = src[t];
    float s0 = v.x, s1 = s0 + v.y, s2 = s1 + v.z, s3 = s2 + v.w;
    float tsum = s3, sc = tsum;
    #pragma unroll
    for (int d = 1; d < 64; d <<= 1) {
        float o = __shfl_up(sc, d, 64);
        if (lane >= d) sc += o;
    }

    __shared__ float wsum[4];
    if (lane == 63) wsum[w] = sc;
    __syncthreads();
    float woff = 0.0f;
    #pragma unroll
    for (int k = 0; k < 4; ++k) woff += (k < w) ? wsum[k] : 0.0f;

    float ex = woff + sc - tsum;
    dst[t] = make_float4(ex + s0, ex + s1, ex + s2, ex + s3);
}

// ---- Pass 2: partial column cumsum per 16-row tile; tile sums -> S ---------
__global__ __launch_bounds__(256) void col_partial(
    float* __restrict__ I, float* __restrict__ Sf)
{
    int b    = blockIdx.x;
    int tile = b % NTIL;
    int cg   = (b / NTIL) % NCOLG;
    int ch   = b / (NTIL * NCOLG);
    int c2   = cg * 256 + threadIdx.x;

    float2* base = (float2*)(I + (size_t)ch * HW + (size_t)(tile * RT) * WW) + c2;
    float2* S2   = (float2*)Sf;

    float2 acc = make_float2(0.0f, 0.0f);
    #pragma unroll
    for (int r = 0; r < RT; ++r) {
        float2 v = base[(size_t)r * (WW / 2)];
        acc.x += v.x; acc.y += v.y;
        base[(size_t)r * (WW / 2)] = acc;
    }
    S2[(size_t)(ch * NTIL + tile) * (WW / 2) + c2] = acc;
}

// ---- Pass 3: inclusive scan of the 64 tile sums per column (wave/column) ---
__global__ __launch_bounds__(256) void scan_S(float* __restrict__ Sf)
{
    int gw   = (blockIdx.x * 256 + threadIdx.x) >> 6;   // global wave id
    int lane = threadIdx.x & 63;
    int c    = gw % WW;
    int ch   = gw / WW;                                 // 0..2

    size_t idx = ((size_t)(ch * NTIL + lane)) * WW + c;
    float v = Sf[idx];
    #pragma unroll
    for (int d = 1; d < 64; d <<= 1) {
        float o = __shfl_up(v, d, 64);
        if (lane >= d) v += o;
    }
    Sf[idx] = v;
}

// ---- Pass 4: add scanned tile offsets (tiles 1..NTIL-1) --------------------
__global__ __launch_bounds__(256) void col_fixup(
    float* __restrict__ I, const float* __restrict__ Sf)
{
    int b    = blockIdx.x;
    int tile = b % (NTIL - 1) + 1;
    int cg   = (b / (NTIL - 1)) % NCOLG;
    int ch   = b / ((NTIL - 1) * NCOLG);
    int c2   = cg * 256 + threadIdx.x;

    const float2* S2 = (const float2*)Sf;
    float2 off = S2[(size_t)(ch * NTIL + tile - 1) * (WW / 2) + c2];

    float2* base = (float2*)(I + (size_t)ch * HW + (size_t)(tile * RT) * WW) + c2;
    #pragma unroll
    for (int r = 0; r < RT; ++r) {
        float2 v = base[(size_t)r * (WW / 2)];
        v.x += off.x; v.y += off.y;
        base[(size_t)r * (WW / 2)] = v;
    }
}

// ---- Pass 5: gather. Block = one output row; stage 2 SAT rows in LDS. ------
// Staged segments are contiguous & coalesced (~(s+1)/8 cache lines for both
// rows vs ~176 for direct taps). Lanes then do 4 LDS reads at lo_j/hi_j.
__global__ __launch_bounds__(256) void cutouts_gather(
    const float* __restrict__ I,
    const int*   __restrict__ sizesv,
    const int*   __restrict__ oyv,
    const int*   __restrict__ oxv,
    float*       __restrict__ out)
{
    __shared__ float lhi[LSEG];
    __shared__ float llo[LSEG];

    int b   = blockIdx.x;              // ((ch*128)+n)*224 + i
    int i   = b % CS;
    int rem = b / CS;
    int n   = rem % 128;
    int ch  = rem / 128;               // slowest: working set = one 4MB plane

    int s   = sizesv[n];
    int oy_ = oyv[n];
    int ox_ = oxv[n];

    int lo_i = (i * s) / CS;
    int nR   = ((i + 1) * s + (CS - 1)) / CS - lo_i;
    int r0   = oy_ + lo_i;
    int r1m  = r0 + nR - 1;
    bool rm  = (r0 > 0);
    int r0m  = rm ? (r0 - 1) : 0;

    const float* Rhi = I + (size_t)ch * HW + (size_t)r1m * WW;
    const float* Rlo = I + (size_t)ch * HW + (size_t)r0m * WW;

    // Stage segment covering image cols [ox-1 .. ox+s-1]: local u <-> col ox-1+u.
    int tid  = threadIdx.x;
    int segN = s + 1;
    for (int u = tid; u < segN; u += 256) {
        int col = ox_ - 1 + u;
        col = col < 0 ? 0 : col;       // u=0 with ox=0: value masked later
        lhi[u] = Rhi[col];
        llo[u] = Rlo[col];
    }
    __syncthreads();

    int j = tid;
    if (j < CS) {
        int lo_j = (j * s) / CS;                       // local acol index
        int hi_j = ((j + 1) * s + (CS - 1)) / CS;      // local bcol index
        bool am  = (ox_ + lo_j) > 0;                   // c0 > 0

        float t11 = lhi[hi_j];
        float t10 = lhi[lo_j];
        float t01 = llo[hi_j];
        float t00 = llo[lo_j];

        float sum = t11
                  - (am ? t10 : 0.0f)
                  - (rm ? t01 : 0.0f)
                  + ((am && rm) ? t00 : 0.0f);

        float area = (float)nR * (float)(hi_j - lo_j);
        out[((size_t)((n * 3 + ch) * CS) + i) * CS + j] =
            sum * __builtin_amdgcn_rcpf(area);
    }
}

extern "C" void kernel_launch(void* const* d_in, const int* in_sizes, int n_in,
                              void* d_out, int out_size, void* d_ws, size_t ws_size,
                              hipStream_t stream) {
    const float* x     = (const float*)d_in[0];
    const int*   sizes = (const int*)d_in[1];
    const int*   oy    = (const int*)d_in[2];
    const int*   ox    = (const int*)d_in[3];
    float*       out   = (float*)d_out;
    float*       I     = (float*)d_ws;               // 12 MB

    // Tile-sum scratch (3*64*1024 floats = 768 KB) in the tail of d_out;
    // fully overwritten by the gather pass afterwards.
    float* S = out + (out_size - 3 * NTIL * WW);

    row_cumsum<<<3 * HH, 256, 0, stream>>>(x, I);
    col_partial<<<3 * NCOLG * NTIL, 256, 0, stream>>>(I, S);
    scan_S<<<(3 * WW) / 4, 256, 0, stream>>>(S);       // 768 blocks, 4 waves each
    col_fixup<<<3 * NCOLG * (NTIL - 1), 256, 0, stream>>>(I, S);

    int blocks = 3 * 128 * CS;                        // 86016
    cutouts_gather<<<blocks, 256, 0, stream>>>(I, sizes, oy, ox, out);
}